// Round 6
// baseline (392.686 us; speedup 1.0000x reference)
//
#include <hip/hip_runtime.h>

// Problem constants (from reference)
#define H_DIM 2048
#define E_DIM 8
#define T_DIM 2048
#define F_DIM 4096                    // INTER*2
#define ROWS (E_DIM * H_DIM)          // 16384 (e,h) rows of W
#define TCHUNK 128
#define TCHUNKS 16
#define A_BLOCKS 32                   // 2 h-halves x 16 t-chunks, dispatched FIRST
#define RS_BLOCKS 1024                // 4 waves/block, 4 CONSECUTIVE rows/wave

typedef float f32x4 __attribute__((ext_vector_type(4)));

// ws layout (floats): [0,ROWS)=Bsum   [ROWS, ROWS+TCHUNKS*ROWS)=Ap partials (1 MB)

__global__ __launch_bounds__(256, 4) void fused_compute(
    const float* __restrict__ hidden,   // [T, H]
    const float* __restrict__ W,        // [E, H, F]
    const float* __restrict__ mask,     // [E, T]
    float* __restrict__ ws,
    float* __restrict__ out) {
  float* Bsum = ws;
  float* Ap   = ws + ROWS;
  int bid = blockIdx.x;
  int tid = threadIdx.x;

  if (bid < A_BLOCKS) {
    // --- A[e,h] partials: Ap[tc][e,h] = sum_{t in chunk} mask[e,t]*hidden[t,h]
    if (bid == 0 && tid == 0) out[0] = 0.f;   // dot kernel accumulates via atomicAdd

    int hb = bid & 1;                // 2 h-halves of 1024 columns
    int tc = bid >> 1;               // 16 t-chunks of 128
    int t0 = tc * TCHUNK;
    int h4 = hb * 1024 + tid * 4;    // each thread owns 4 consecutive h

    __shared__ float m_lds[E_DIM][TCHUNK];   // 4 KB
    #pragma unroll
    for (int i = 0; i < (E_DIM * TCHUNK) / 256; ++i) {   // 4 iters
      int idx = i * 256 + tid;
      int e = idx >> 7, tt = idx & 127;
      m_lds[e][tt] = mask[e * T_DIM + t0 + tt];
    }
    __syncthreads();

    f32x4 acc[E_DIM];
    #pragma unroll
    for (int e = 0; e < E_DIM; ++e) acc[e] = (f32x4)0.f;
    #pragma unroll 2
    for (int t = 0; t < TCHUNK; ++t) {
      f32x4 hv = *(const f32x4*)(hidden + (size_t)(t0 + t) * H_DIM + h4);
      #pragma unroll
      for (int e = 0; e < E_DIM; ++e)
        acc[e] += hv * m_lds[e][t];          // wave-uniform LDS broadcast
    }
    #pragma unroll
    for (int e = 0; e < E_DIM; ++e)
      *(f32x4*)(Ap + (size_t)tc * ROWS + e * H_DIM + h4) = acc[e];
  } else {
    // --- B[row] = sum_f W[row,f].  One wave streams 4 CONSECUTIVE rows =
    //     one contiguous 64 KB region. 64 fully-unrolled independent loads,
    //     4 independent accumulator chains -> deep MLP.
    int wv   = ((bid - A_BLOCKS) << 2) | (tid >> 6);   // 0..4095
    int lane = tid & 63;
    const f32x4* base = (const f32x4*)W + (size_t)wv * 4096 + lane;

    f32x4 acc[4];
    #pragma unroll
    for (int r = 0; r < 4; ++r) acc[r] = (f32x4)0.f;
    #pragma unroll
    for (int i = 0; i < 64; ++i)           // 64 x 1KB coalesced wave reads
      acc[i >> 4] += base[i << 6];

    float s[4];
    #pragma unroll
    for (int r = 0; r < 4; ++r)
      s[r] = (acc[r].x + acc[r].y) + (acc[r].z + acc[r].w);
    #pragma unroll
    for (int off = 32; off > 0; off >>= 1) {
      #pragma unroll
      for (int r = 0; r < 4; ++r)
        s[r] += __shfl_down(s[r], off, 64);
    }
    if (lane == 0) {
      #pragma unroll
      for (int r = 0; r < 4; ++r)
        Bsum[wv * 4 + r] = s[r];
    }
  }
}

// 4 blocks x 1024 threads; thread i handles one f32x4 row-group.
__global__ __launch_bounds__(1024) void dot_kernel(const float* __restrict__ ws,
                                                   float* __restrict__ out) {
  const f32x4* B4 = (const f32x4*)ws;
  const f32x4* A4 = (const f32x4*)(ws + ROWS);
  int i = blockIdx.x * 1024 + threadIdx.x;    // 0 .. ROWS/4-1

  f32x4 a = (f32x4)0.f;
  #pragma unroll
  for (int c = 0; c < TCHUNKS; ++c)
    a += A4[(size_t)c * (ROWS / 4) + i];
  f32x4 b = B4[i];
  float s = (a.x * b.x + a.y * b.y) + (a.z * b.z + a.w * b.w);

  #pragma unroll
  for (int off = 32; off > 0; off >>= 1)
    s += __shfl_down(s, off, 64);

  __shared__ float red[16];
  int wave = threadIdx.x >> 6;
  int lane = threadIdx.x & 63;
  if (lane == 0) red[wave] = s;
  __syncthreads();
  if (threadIdx.x == 0) {
    float r = 0.f;
    #pragma unroll
    for (int w = 0; w < 16; ++w) r += red[w];
    atomicAdd(out, r);
  }
}

extern "C" void kernel_launch(void* const* d_in, const int* in_sizes, int n_in,
                              void* d_out, int out_size, void* d_ws, size_t ws_size,
                              hipStream_t stream) {
  const float* hidden = (const float*)d_in[0];  // [1,1,T,H] fp32
  const float* W      = (const float*)d_in[1];  // [1,E,H,2*INTER] fp32
  const float* mask   = (const float*)d_in[2];  // [1,E,T,1] fp32
  float* out = (float*)d_out;                   // scalar
  float* ws  = (float*)d_ws;

  fused_compute<<<A_BLOCKS + RS_BLOCKS, 256, 0, stream>>>(hidden, W, mask, ws, out);
  dot_kernel<<<4, 1024, 0, stream>>>(ws, out);
}